// Round 2
// baseline (7616.039 us; speedup 1.0000x reference)
//
#include <hip/hip_runtime.h>
#include <stdint.h>

// MixBlock3D: B=2 C=256 D=8 H=56 W=56, GWS=(2,7,7) -> no padding needed.
// I/O float32 (per reference dtypes). Intermediates bf16, compute fp32.

typedef unsigned short u16;

#define TOK   50176   // B*D*H*W
#define CH    256
#define SPAT  25088   // D*H*W
#define PLANE 3136    // H*W

__device__ __forceinline__ float b2f(u16 u) {
    union { uint32_t i; float f; } v; v.i = ((uint32_t)u) << 16; return v.f;
}
__device__ __forceinline__ u16 f2b(float f) {
    union { float f; uint32_t i; } v; v.f = f;
    uint32_t i = v.i;
    uint32_t r = i + 0x7FFFu + ((i >> 16) & 1u);   // round-to-nearest-even
    return (u16)(r >> 16);
}

// ---------------- LN1: NCDHW f32 -> token-major (t, c) bf16 -----------------
__global__ __launch_bounds__(256) void ln1_kernel(
    const float* __restrict__ x, const float* __restrict__ w,
    const float* __restrict__ bsh, u16* __restrict__ out)
{
    int t = blockIdx.x * 256 + threadIdx.x;           // 50176 exact
    int b = t / SPAT, sp = t % SPAT;
    const float* px = x + (size_t)b * CH * SPAT + sp; // channel stride SPAT
    float s = 0.f, ss = 0.f;
    for (int c = 0; c < CH; c++) { float v = px[(size_t)c * SPAT]; s += v; ss += v * v; }
    float mean = s * (1.0f / CH);
    float var  = ss * (1.0f / CH) - mean * mean;
    float rstd = rsqrtf(var + 1e-5f);
    u16* po = out + (size_t)t * CH;
    for (int c = 0; c < CH; c++) {
        float v = (px[(size_t)c * SPAT] - mean) * rstd * w[c] + bsh[c];
        po[c] = f2b(v);
    }
}

// ---------------- LN2: token-major bf16 -> token-major bf16 -----------------
__global__ __launch_bounds__(256) void ln2_kernel(
    const u16* __restrict__ x, const float* __restrict__ w,
    const float* __restrict__ bsh, u16* __restrict__ out)
{
    int wave = threadIdx.x >> 6, lane = threadIdx.x & 63;
    int t = blockIdx.x * 4 + wave;                    // 12544*4 = 50176 exact
    const u16* px = x + (size_t)t * CH + lane * 4;
    ushort4 v4 = *(const ushort4*)px;
    float v0 = b2f(v4.x), v1 = b2f(v4.y), v2 = b2f(v4.z), v3 = b2f(v4.w);
    float s = v0 + v1 + v2 + v3;
    float ss = v0*v0 + v1*v1 + v2*v2 + v3*v3;
    for (int o = 32; o > 0; o >>= 1) {
        s  += __shfl_xor(s,  o, 64);
        ss += __shfl_xor(ss, o, 64);
    }
    float mean = s * (1.0f / CH);
    float rstd = rsqrtf(ss * (1.0f / CH) - mean * mean + 1e-5f);
    float4 w4 = *(const float4*)(w + lane * 4);
    float4 b4 = *(const float4*)(bsh + lane * 4);
    ushort4 o4;
    o4.x = f2b((v0 - mean) * rstd * w4.x + b4.x);
    o4.y = f2b((v1 - mean) * rstd * w4.y + b4.y);
    o4.z = f2b((v2 - mean) * rstd * w4.z + b4.z);
    o4.w = f2b((v3 - mean) * rstd * w4.w + b4.w);
    *(ushort4*)(out + (size_t)t * CH + lane * 4) = o4;
}

// -------- GEMM: C[M,N] = A[M,256](bf16) @ B[N,256]^T(f32) (+bias f32)(+res bf16)
// 64x64 tile, BK=64 chunks staged to LDS as fp32, 4x4 per thread.
__global__ __launch_bounds__(256) void gemm_bt_kernel(
    const u16* __restrict__ A, const float* __restrict__ B,
    const float* __restrict__ bias, const u16* __restrict__ res,
    u16* __restrict__ C, int N)
{
    __shared__ float sA[64][68];
    __shared__ float sB[64][68];
    int m0 = blockIdx.x * 64, n0 = blockIdx.y * 64;
    int tid = threadIdx.x;
    int tr = tid >> 4, tc = tid & 15;
    float acc[4][4] = {};

    for (int kc = 0; kc < 256; kc += 64) {
        // stage A tile: 64 rows x 64 k (8 bf16 per unit, 512 units)
        for (int v = tid; v < 512; v += 256) {
            int mm = v >> 3, k8 = (v & 7) * 8;
            uint4 r = *(const uint4*)(A + (size_t)(m0 + mm) * 256 + kc + k8);
            float* d = &sA[mm][k8];
            d[0] = b2f((u16)(r.x & 0xffff)); d[1] = b2f((u16)(r.x >> 16));
            d[2] = b2f((u16)(r.y & 0xffff)); d[3] = b2f((u16)(r.y >> 16));
            d[4] = b2f((u16)(r.z & 0xffff)); d[5] = b2f((u16)(r.z >> 16));
            d[6] = b2f((u16)(r.w & 0xffff)); d[7] = b2f((u16)(r.w >> 16));
        }
        // stage B tile: 64 rows x 64 k (4 f32 per unit, 1024 units)
        for (int v = tid; v < 1024; v += 256) {
            int nn = v >> 4, k4 = (v & 15) * 4;
            float4 r = *(const float4*)(B + (size_t)(n0 + nn) * 256 + kc + k4);
            float* d = &sB[nn][k4];
            d[0] = r.x; d[1] = r.y; d[2] = r.z; d[3] = r.w;
        }
        __syncthreads();
        #pragma unroll
        for (int k4 = 0; k4 < 16; k4++) {
            float4 av[4], bv[4];
            #pragma unroll
            for (int i = 0; i < 4; i++) av[i] = *(const float4*)&sA[tr*4 + i][k4*4];
            #pragma unroll
            for (int j = 0; j < 4; j++) bv[j] = *(const float4*)&sB[tc*4 + j][k4*4];
            #pragma unroll
            for (int i = 0; i < 4; i++)
                #pragma unroll
                for (int j = 0; j < 4; j++)
                    acc[i][j] += av[i].x*bv[j].x + av[i].y*bv[j].y
                               + av[i].z*bv[j].z + av[i].w*bv[j].w;
        }
        __syncthreads();
    }

    #pragma unroll
    for (int i = 0; i < 4; i++) {
        size_t row = (size_t)(m0 + tr*4 + i) * N;
        #pragma unroll
        for (int j = 0; j < 4; j++) {
            int n = n0 + tc*4 + j;
            float v = acc[i][j];
            if (bias) v += bias[n];
            if (res)  v += b2f(res[row + n]);
            C[row + n] = f2b(v);
        }
    }
}

// ---------------- Attention: one block per (group, head) --------------------
// mode 0 = window partition, mode 1 = grid partition. N=98 tokens, hd=64.
__global__ __launch_bounds__(256) void attn_kernel(
    const u16* __restrict__ qkv, const float* __restrict__ btab,
    u16* __restrict__ outp, int mode)
{
    __shared__ u16 sQ[98][68];
    __shared__ u16 sK[98][68];
    __shared__ u16 sV[98][68];
    __shared__ u16 sS[98][100];
    __shared__ int sTok[98];

    int g = blockIdx.x, head = blockIdx.y, tid = threadIdx.x;
    int b  = g >> 8;
    int gd = (g >> 6) & 3, gh = (g >> 3) & 7, gw = g & 7;

    if (tid < 98) {
        int i = tid / 49, r = tid % 49, j = r / 7, k = r % 7;
        int d, h, w;
        if (mode == 0) { d = gd*2 + i; h = gh*7 + j; w = gw*7 + k; }
        else           { d = i*4 + gd; h = j*8 + gh; w = k*8 + gw; }
        sTok[tid] = ((b*8 + d)*56 + h)*56 + w;
    }
    __syncthreads();

    for (int idx = tid; idx < 98*64; idx += 256) {
        int n = idx >> 6, c = idx & 63;
        const u16* p = qkv + (size_t)sTok[n] * 768 + head * 64 + c;
        sQ[n][c] = f2b(b2f(p[0]) * 0.125f);   // SCALE = 1/sqrt(64)
        sK[n][c] = p[256];
        sV[n][c] = p[512];
    }
    __syncthreads();

    for (int idx = tid; idx < 98*98; idx += 256) {
        int n = idx / 98, m = idx % 98;
        const ushort4* q4 = (const ushort4*)sQ[n];
        const ushort4* k4 = (const ushort4*)sK[m];
        float dot = 0.f;
        #pragma unroll
        for (int c4 = 0; c4 < 16; c4++) {
            ushort4 qa = q4[c4], kb = k4[c4];
            dot += b2f(qa.x)*b2f(kb.x) + b2f(qa.y)*b2f(kb.y)
                 + b2f(qa.z)*b2f(kb.z) + b2f(qa.w)*b2f(kb.w);
        }
        int i1 = n / 49, r1 = n % 49, j1 = r1 / 7, k1 = r1 % 7;
        int i2 = m / 49, r2 = m % 49, j2 = r2 / 7, k2 = r2 % 7;
        int rpi = (i1 - i2 + 1)*169 + (j1 - j2 + 6)*13 + (k1 - k2 + 6);
        dot += btab[rpi * 4 + head];
        sS[n][m] = f2b(dot);
    }
    __syncthreads();

    if (tid < 98) {
        float mx = -1e30f;
        for (int m = 0; m < 98; m++) mx = fmaxf(mx, b2f(sS[tid][m]));
        float sum = 0.f;
        for (int m = 0; m < 98; m++) {
            float e = __expf(b2f(sS[tid][m]) - mx);
            sum += e;
            sS[tid][m] = f2b(e);
        }
        float inv = 1.0f / sum;
        for (int m = 0; m < 98; m++) sS[tid][m] = f2b(b2f(sS[tid][m]) * inv);
    }
    __syncthreads();

    for (int idx = tid; idx < 98*64; idx += 256) {
        int n = idx >> 6, c = idx & 63;
        float acc = 0.f;
        for (int m = 0; m < 98; m++) acc += b2f(sS[n][m]) * b2f(sV[m][c]);
        outp[(size_t)sTok[n] * 256 + head * 64 + c] = f2b(acc);
    }
}

// ---- s = input(f32) + y(bf16 token-major); split to s1/s2 (bf16, NCDHW) ----
__global__ __launch_bounds__(256) void ssplit_kernel(
    const float* __restrict__ inp, const u16* __restrict__ y,
    u16* __restrict__ s1, u16* __restrict__ s2)
{
    int e = blockIdx.x * 256 + threadIdx.x;   // 2*256*25088 exact
    int b = e / (CH * SPAT);
    int c = (e / SPAT) & 255;
    int sp = e % SPAT;
    float v = inp[e] + b2f(y[(size_t)(b * SPAT + sp) * CH + c]);
    if (c < 128) s1[(size_t)(b*128 + c)       * SPAT + sp] = f2b(v);
    else         s2[(size_t)(b*128 + c - 128) * SPAT + sp] = f2b(v);
}

// ---------------- direct 3x3x3 conv, 128->128, SAME -------------------------
// one block per (b,d,h) row; thread = (oc, half); 28 outputs along w each.
// in/out dtype selectable: bf16 scratch or f32 (d_out). weights/bias f32.
__global__ __launch_bounds__(256) void conv3d_kernel(
    const void* __restrict__ inv, int in_f32, int inBS,
    const float* __restrict__ wt, const float* __restrict__ bias,
    const u16* __restrict__ res, int resBS,
    void* __restrict__ outv, int out_f32, int outBS, int leaky)
{
    int bid = blockIdx.x;                       // b*448 + d*56 + h
    int b = bid / 448, r0 = bid % 448, d = r0 / 56, h = r0 % 56;
    int tid = threadIdx.x, oc = tid >> 1, half = tid & 1;
    __shared__ float sIn[9][60];

    float acc[28];
    float bv = bias[oc];
    #pragma unroll
    for (int i = 0; i < 28; i++) acc[i] = bv;

    for (int ic = 0; ic < 128; ic++) {
        __syncthreads();
        for (int idx = tid; idx < 522; idx += 256) {   // 9 rows x 58 (w=-1..56)
            int rr = idx / 58, x = idx % 58;
            int dd = d + rr / 3 - 1, hh = h + rr % 3 - 1;
            float v = 0.f;
            if (dd >= 0 && dd < 8 && hh >= 0 && hh < 56 && x >= 1 && x <= 56) {
                size_t off = (size_t)b * inBS + (size_t)ic * SPAT + (dd * 56 + hh) * 56 + (x - 1);
                v = in_f32 ? ((const float*)inv)[off] : b2f(((const u16*)inv)[off]);
            }
            sIn[rr][x] = v;
        }
        __syncthreads();
        const float* wp = wt + ((size_t)oc * 128 + ic) * 27;
        #pragma unroll
        for (int kd = 0; kd < 3; kd++)
        {
            #pragma unroll
            for (int kh = 0; kh < 3; kh++) {
                const float* row = sIn[kd*3 + kh];
                float w0 = wp[(kd*3 + kh)*3 + 0];
                float w1 = wp[(kd*3 + kh)*3 + 1];
                float w2 = wp[(kd*3 + kh)*3 + 2];
                float rv[30];
                #pragma unroll
                for (int i = 0; i < 30; i++) rv[i] = row[half*28 + i];
                #pragma unroll
                for (int i = 0; i < 28; i++)
                    acc[i] += rv[i]*w0 + rv[i+1]*w1 + rv[i+2]*w2;
            }
        }
    }

    int spBase = (d * 56 + h) * 56 + half * 28;
    #pragma unroll
    for (int i = 0; i < 28; i++) {
        float v = acc[i];
        if (leaky) v = (v >= 0.f) ? v : 0.01f * v;
        if (res)  v += b2f(res[(size_t)b * resBS + (size_t)oc * SPAT + spBase + i]);
        size_t off = (size_t)b * outBS + (size_t)oc * SPAT + spBase + i;
        if (out_f32) ((float*)outv)[off] = v;
        else         ((u16*)outv)[off] = f2b(v);
    }
}

// ---------------- launch ----------------------------------------------------
extern "C" void kernel_launch(void* const* d_in, const int* in_sizes, int n_in,
                              void* d_out, int out_size, void* d_ws, size_t ws_size,
                              hipStream_t stream)
{
    const float* input  = (const float*)d_in[0];
    const float* n1w    = (const float*)d_in[1];
    const float* n1b    = (const float*)d_in[2];
    const float* n2w    = (const float*)d_in[3];
    const float* n2b    = (const float*)d_in[4];
    const float* wqkv   = (const float*)d_in[5];
    const float* wprojw = (const float*)d_in[6];
    const float* wprojb = (const float*)d_in[7];
    const float* wbias  = (const float*)d_in[8];
    const float* gqkv   = (const float*)d_in[9];
    const float* gprojw = (const float*)d_in[10];
    const float* gprojb = (const float*)d_in[11];
    const float* gbias  = (const float*)d_in[12];
    const float* f1c1w  = (const float*)d_in[13];
    const float* f1c1b  = (const float*)d_in[14];
    const float* f1c2w  = (const float*)d_in[15];
    const float* f1c2b  = (const float*)d_in[16];
    const float* g1c1w  = (const float*)d_in[17];
    const float* g1c1b  = (const float*)d_in[18];
    const float* g1c2w  = (const float*)d_in[19];
    const float* g1c2b  = (const float*)d_in[20];

    char* ws = (char*)d_ws;
    // layout (bytes), all bf16 intermediates:
    u16* xln   = (u16*)(ws);                    // 50176*256*2 = 25,690,112 (later: y)
    u16* qkv   = (u16*)(ws + 25690112);         // 50176*768*2 = 77,070,336 (later: s1,s2,tb)
    u16* attnb = (u16*)(ws + 102760448);        // 25,690,112
    u16* xw    = (u16*)(ws + 128450560);        // 25,690,112  -> total 154,140,672
    u16* y  = xln;                              // xln dead after grid qkv gemm
    u16* s1 = qkv;                              // 2*128*25088 = 6,422,528 elems
    u16* s2 = qkv + 6422528;
    u16* tb = qkv + 12845056;

    float* outp = (float*)d_out;

    // 1) LN1 (f32 in -> bf16 token-major)
    ln1_kernel<<<196, 256, 0, stream>>>(input, n1w, n1b, xln);
    // 2) window qkv
    gemm_bt_kernel<<<dim3(784, 12), 256, 0, stream>>>(xln, wqkv, nullptr, nullptr, qkv, 768);
    // 3) window attention
    attn_kernel<<<dim3(512, 4), 256, 0, stream>>>(qkv, wbias, attnb, 0);
    // 4) window proj -> xw
    gemm_bt_kernel<<<dim3(784, 4), 256, 0, stream>>>(attnb, wprojw, wprojb, nullptr, xw, 256);
    // 5) LN2 -> xln (reuse)
    ln2_kernel<<<12544, 256, 0, stream>>>(xw, n2w, n2b, xln);
    // 6) grid qkv
    gemm_bt_kernel<<<dim3(784, 12), 256, 0, stream>>>(xln, gqkv, nullptr, nullptr, qkv, 768);
    // 7) grid attention
    attn_kernel<<<dim3(512, 4), 256, 0, stream>>>(qkv, gbias, attnb, 1);
    // 8) grid proj + xw residual -> y (aliases xln, safe: xln dead)
    gemm_bt_kernel<<<dim3(784, 4), 256, 0, stream>>>(attnb, gprojw, gprojb, xw, y, 256);
    // 9) s = input + y, split NCDHW halves (overwrites qkv region)
    ssplit_kernel<<<50176, 256, 0, stream>>>(input, y, s1, s2);
    // 10) t = leaky(conv(s2, f1c1))          bf16 -> bf16
    conv3d_kernel<<<896, 256, 0, stream>>>(s2, 0, 128*SPAT, f1c1w, f1c1b, nullptr, 0, tb, 0, 128*SPAT, 1);
    // 11) y1 = s1 + conv(t, f1c2) -> out[:,0:128]   bf16 -> f32
    conv3d_kernel<<<896, 256, 0, stream>>>(tb, 0, 128*SPAT, f1c2w, f1c2b, s1, 128*SPAT, outp, 1, 256*SPAT, 0);
    // 12) t = leaky(conv(y1, g1c1))          f32(d_out) -> bf16
    conv3d_kernel<<<896, 256, 0, stream>>>(outp, 1, 256*SPAT, g1c1w, g1c1b, nullptr, 0, tb, 0, 128*SPAT, 1);
    // 13) y2 = s2 + conv(t, g1c2) -> out[:,128:256] bf16 -> f32
    conv3d_kernel<<<896, 256, 0, stream>>>(tb, 0, 128*SPAT, g1c2w, g1c2b, s2, 128*SPAT, outp + (size_t)128*SPAT, 1, 256*SPAT, 0);
}

// Round 4
// 1815.411 us; speedup vs baseline: 4.1952x; 4.1952x over previous
//
#include <hip/hip_runtime.h>
#include <stdint.h>

// MixBlock3D: B=2 C=256 D=8 H=56 W=56, GWS=(2,7,7). I/O f32, intermediates bf16.
// Round 4: fix conv_mfma epilogue — residual now added to the accumulator
// (both out_cl and out_f32 paths), was f32-path-only (y1cl missed +s1).

typedef unsigned short u16;
typedef __attribute__((ext_vector_type(8))) short short8;  // 8 bf16 = 4 VGPR
typedef __attribute__((ext_vector_type(4))) float f32x4;   // 4 fp32 acc

#define TOK   50176
#define CH    256
#define SPAT  25088
#define PLANE 3136

__device__ __forceinline__ float b2f(u16 u) {
    union { uint32_t i; float f; } v; v.i = ((uint32_t)u) << 16; return v.f;
}
__device__ __forceinline__ u16 f2b(float f) {
    union { float f; uint32_t i; } v; v.f = f;
    uint32_t i = v.i;
    uint32_t r = i + 0x7FFFu + ((i >> 16) & 1u);
    return (u16)(r >> 16);
}

// ---------------- LN1: NCDHW f32 -> token-major (t, c) bf16 -----------------
__global__ __launch_bounds__(256) void ln1_kernel(
    const float* __restrict__ x, const float* __restrict__ w,
    const float* __restrict__ bsh, u16* __restrict__ out)
{
    int t = blockIdx.x * 256 + threadIdx.x;
    int b = t / SPAT, sp = t % SPAT;
    const float* px = x + (size_t)b * CH * SPAT + sp;
    float s = 0.f, ss = 0.f;
    for (int c = 0; c < CH; c++) { float v = px[(size_t)c * SPAT]; s += v; ss += v * v; }
    float mean = s * (1.0f / CH);
    float var  = ss * (1.0f / CH) - mean * mean;
    float rstd = rsqrtf(var + 1e-5f);
    u16* po = out + (size_t)t * CH;
    for (int c = 0; c < CH; c++) {
        float v = (px[(size_t)c * SPAT] - mean) * rstd * w[c] + bsh[c];
        po[c] = f2b(v);
    }
}

// ---------------- LN2: token-major bf16 -> token-major bf16 -----------------
__global__ __launch_bounds__(256) void ln2_kernel(
    const u16* __restrict__ x, const float* __restrict__ w,
    const float* __restrict__ bsh, u16* __restrict__ out)
{
    int wave = threadIdx.x >> 6, lane = threadIdx.x & 63;
    int t = blockIdx.x * 4 + wave;
    const u16* px = x + (size_t)t * CH + lane * 4;
    ushort4 v4 = *(const ushort4*)px;
    float v0 = b2f(v4.x), v1 = b2f(v4.y), v2 = b2f(v4.z), v3 = b2f(v4.w);
    float s = v0 + v1 + v2 + v3;
    float ss = v0*v0 + v1*v1 + v2*v2 + v3*v3;
    for (int o = 32; o > 0; o >>= 1) {
        s  += __shfl_xor(s,  o, 64);
        ss += __shfl_xor(ss, o, 64);
    }
    float mean = s * (1.0f / CH);
    float rstd = rsqrtf(ss * (1.0f / CH) - mean * mean + 1e-5f);
    float4 w4 = *(const float4*)(w + lane * 4);
    float4 b4 = *(const float4*)(bsh + lane * 4);
    ushort4 o4;
    o4.x = f2b((v0 - mean) * rstd * w4.x + b4.x);
    o4.y = f2b((v1 - mean) * rstd * w4.y + b4.y);
    o4.z = f2b((v2 - mean) * rstd * w4.z + b4.z);
    o4.w = f2b((v3 - mean) * rstd * w4.w + b4.w);
    *(ushort4*)(out + (size_t)t * CH + lane * 4) = o4;
}

// ---- MFMA GEMM: C[M,Nout slice] = A[M,256](bf16) @ B[N,256]^T(f32 weights) ----
// 128x128 tile, BK=64, 4 waves x (64x64). B converted f32->bf16 during staging.
__global__ __launch_bounds__(256) void gemm_mfma_kernel(
    const u16* __restrict__ A, const float* __restrict__ B,
    const float* __restrict__ bias, const u16* __restrict__ res,
    u16* __restrict__ C, int Nout)
{
    __shared__ u16 sAg[128][72];
    __shared__ u16 sBg[128][72];
    int tid = threadIdx.x;
    int m0 = blockIdx.x * 128, n0g = blockIdx.y * 128;
    int lane = tid & 63, wv = tid >> 6;
    int quad = lane >> 4, l15 = lane & 15;
    int mw = (wv & 1) * 64, nw = (wv >> 1) * 64;

    f32x4 zz = {0.f, 0.f, 0.f, 0.f};
    f32x4 acc[4][4];
    #pragma unroll
    for (int i = 0; i < 4; i++)
        #pragma unroll
        for (int j = 0; j < 4; j++) acc[i][j] = zz;

    for (int kc = 0; kc < 256; kc += 64) {
        __syncthreads();
        #pragma unroll
        for (int i = 0; i < 4; i++) {
            int unit = tid + i * 256;
            int row = unit >> 3, k8 = (unit & 7) << 3;
            *(uint4*)&sAg[row][k8] = *(const uint4*)(A + (size_t)(m0 + row) * 256 + kc + k8);
        }
        #pragma unroll
        for (int i = 0; i < 8; i++) {
            int unit = tid + i * 256;
            int row = unit >> 4, k4 = (unit & 15) << 2;
            float4 v = *(const float4*)(B + (size_t)(n0g + row) * 256 + kc + k4);
            ushort4 p;
            p.x = f2b(v.x); p.y = f2b(v.y); p.z = f2b(v.z); p.w = f2b(v.w);
            *(ushort4*)&sBg[row][k4] = p;
        }
        __syncthreads();
        #pragma unroll
        for (int kk = 0; kk < 2; kk++) {
            short8 afr[4], bfr[4];
            #pragma unroll
            for (int mt = 0; mt < 4; mt++)
                afr[mt] = *(const short8*)&sAg[mw + mt*16 + l15][kk*32 + quad*8];
            #pragma unroll
            for (int nt = 0; nt < 4; nt++)
                bfr[nt] = *(const short8*)&sBg[nw + nt*16 + l15][kk*32 + quad*8];
            #pragma unroll
            for (int mt = 0; mt < 4; mt++)
                #pragma unroll
                for (int nt = 0; nt < 4; nt++)
                    acc[mt][nt] = __builtin_amdgcn_mfma_f32_16x16x32_bf16(
                        afr[mt], bfr[nt], acc[mt][nt], 0, 0, 0);
        }
    }

    #pragma unroll
    for (int nt = 0; nt < 4; nt++) {
        int n = n0g + nw + nt*16 + l15;
        float bv = bias ? bias[n] : 0.f;
        #pragma unroll
        for (int mt = 0; mt < 4; mt++) {
            int m = m0 + mw + mt*16 + quad*4;
            #pragma unroll
            for (int r = 0; r < 4; r++) {
                float v = acc[mt][nt][r] + bv;
                size_t off = (size_t)(m + r) * Nout + n;
                if (res) v += b2f(res[off]);
                C[off] = f2b(v);
            }
        }
    }
}

// ---------------- Attention: one block per (group, head) --------------------
__global__ __launch_bounds__(256) void attn_kernel(
    const u16* __restrict__ qkv, const float* __restrict__ btab,
    u16* __restrict__ outp, int mode)
{
    __shared__ u16 sQ[98][68];
    __shared__ u16 sK[98][68];
    __shared__ u16 sV[98][68];
    __shared__ u16 sS[98][100];
    __shared__ int sTok[98];

    int g = blockIdx.x, head = blockIdx.y, tid = threadIdx.x;
    int b  = g >> 8;
    int gd = (g >> 6) & 3, gh = (g >> 3) & 7, gw = g & 7;

    if (tid < 98) {
        int i = tid / 49, r = tid % 49, j = r / 7, k = r % 7;
        int d, h, w;
        if (mode == 0) { d = gd*2 + i; h = gh*7 + j; w = gw*7 + k; }
        else           { d = i*4 + gd; h = j*8 + gh; w = k*8 + gw; }
        sTok[tid] = ((b*8 + d)*56 + h)*56 + w;
    }
    __syncthreads();

    for (int idx = tid; idx < 98*64; idx += 256) {
        int n = idx >> 6, c = idx & 63;
        const u16* p = qkv + (size_t)sTok[n] * 768 + head * 64 + c;
        sQ[n][c] = f2b(b2f(p[0]) * 0.125f);
        sK[n][c] = p[256];
        sV[n][c] = p[512];
    }
    __syncthreads();

    for (int idx = tid; idx < 98*98; idx += 256) {
        int n = idx / 98, m = idx % 98;
        const ushort4* q4 = (const ushort4*)sQ[n];
        const ushort4* k4 = (const ushort4*)sK[m];
        float dot = 0.f;
        #pragma unroll
        for (int c4 = 0; c4 < 16; c4++) {
            ushort4 qa = q4[c4], kb = k4[c4];
            dot += b2f(qa.x)*b2f(kb.x) + b2f(qa.y)*b2f(kb.y)
                 + b2f(qa.z)*b2f(kb.z) + b2f(qa.w)*b2f(kb.w);
        }
        int i1 = n / 49, r1 = n % 49, j1 = r1 / 7, k1 = r1 % 7;
        int i2 = m / 49, r2 = m % 49, j2 = r2 / 7, k2 = r2 % 7;
        int rpi = (i1 - i2 + 1)*169 + (j1 - j2 + 6)*13 + (k1 - k2 + 6);
        dot += btab[rpi * 4 + head];
        sS[n][m] = f2b(dot);
    }
    __syncthreads();

    if (tid < 98) {
        float mx = -1e30f;
        for (int m = 0; m < 98; m++) mx = fmaxf(mx, b2f(sS[tid][m]));
        float sum = 0.f;
        for (int m = 0; m < 98; m++) {
            float e = __expf(b2f(sS[tid][m]) - mx);
            sum += e;
            sS[tid][m] = f2b(e);
        }
        float inv = 1.0f / sum;
        for (int m = 0; m < 98; m++) sS[tid][m] = f2b(b2f(sS[tid][m]) * inv);
    }
    __syncthreads();

    for (int idx = tid; idx < 98*64; idx += 256) {
        int n = idx >> 6, c = idx & 63;
        float acc = 0.f;
        for (int m = 0; m < 98; m++) acc += b2f(sS[n][m]) * b2f(sV[m][c]);
        outp[(size_t)sTok[n] * 256 + head * 64 + c] = f2b(acc);
    }
}

// ---- s = input(f32 NCDHW) + y(bf16 token-major) -> s1/s2 channel-last bf16 --
__global__ __launch_bounds__(256) void ssplit_cl_kernel(
    const float* __restrict__ inp, const u16* __restrict__ y,
    u16* __restrict__ s1, u16* __restrict__ s2)
{
    __shared__ float sT[64][65];
    int t0 = blockIdx.x * 64;
    int b = t0 / SPAT, sp0 = t0 % SPAT;
    int tid = threadIdx.x;
    for (int cg = 0; cg < 4; cg++) {
        __syncthreads();
        #pragma unroll
        for (int i = 0; i < 16; i++) {
            int unit = tid + i * 256;
            int cl = unit >> 6, spl = unit & 63;
            sT[spl][cl] = inp[((size_t)(b * 256 + cg * 64 + cl)) * SPAT + sp0 + spl];
        }
        __syncthreads();
        int spl = tid >> 2, c16 = (tid & 3) * 16;
        int tok = t0 + spl;
        const u16* yp = y + (size_t)tok * 256 + cg * 64 + c16;
        int cbase = cg * 64 + c16;
        u16* dst = (cbase < 128) ? (s1 + (size_t)tok * 128 + cbase)
                                 : (s2 + (size_t)tok * 128 + cbase - 128);
        #pragma unroll
        for (int j = 0; j < 16; j++) {
            float v = sT[spl][c16 + j] + b2f(yp[j]);
            dst[j] = f2b(v);
        }
    }
}

// ---- conv weight transform: f32 [oc][ic][27] -> bf16 [27][oc][ic] ----------
__global__ __launch_bounds__(256) void convw_kernel(
    const float* __restrict__ w, u16* __restrict__ o)
{
    int e = blockIdx.x * 256 + threadIdx.x;   // 442368 = 1728*256
    int k = e >> 14;
    int r = e & 16383;                         // oc*128+ic
    o[e] = f2b(w[(size_t)r * 27 + k]);
}

// ---- MFMA conv 3x3x3 128->128, implicit GEMM, channel-last -----------------
// block: 64 tokens x 128 oc. Loop 27 taps x 4 ic-chunks(32). 864 MFMA/wave.
__global__ __launch_bounds__(256) void conv_mfma_kernel(
    const u16* __restrict__ in_cl,   // [tok][128] bf16
    const u16* __restrict__ wt27,    // [27][128 oc][128 ic] bf16
    const float* __restrict__ bias,  // [128] f32
    const u16* __restrict__ res_cl,  // nullable [tok][128] bf16 (added to acc)
    u16* __restrict__ out_cl,        // nullable [tok][128] bf16
    float* __restrict__ out_f32,     // nullable NCDHW f32 (256-ch layout)
    int oc_base, int leaky)
{
    __shared__ u16 sA[64][136];      // 17,408 B (pad 8: 2-way banks, free)
    __shared__ u16 sB[128][136];     // 34,816 B ; reused as f32 [128][65]
    __shared__ int sD[64], sHH[64], sWW[64];

    int tid = threadIdx.x;
    int t0 = blockIdx.x * 64;
    int b = t0 / SPAT, sp0 = t0 % SPAT;

    if (tid < 64) {
        int sp = sp0 + tid;
        int d = sp / PLANE, r = sp % PLANE;
        sD[tid] = d; sHH[tid] = r / 56; sWW[tid] = r % 56;
    }

    int lane = tid & 63, wv = tid >> 6;
    int quad = lane >> 4, l15 = lane & 15;
    int n0 = wv * 32;

    f32x4 zz = {0.f, 0.f, 0.f, 0.f};
    f32x4 acc[4][2];
    #pragma unroll
    for (int i = 0; i < 4; i++) { acc[i][0] = zz; acc[i][1] = zz; }

    __syncthreads();

    for (int ko = 0; ko < 27; ko++) {
        int kd = ko / 9 - 1, kh = (ko / 3) % 3 - 1, kw = ko % 3 - 1;
        __syncthreads();
        // stage A: gathered neighbor rows, 64 tokens x 128 ic
        #pragma unroll
        for (int i = 0; i < 4; i++) {
            int unit = tid + i * 256;
            int m = unit >> 4, k8 = (unit & 15) << 3;
            int dd = sD[m] + kd, hh = sHH[m] + kh, ww = sWW[m] + kw;
            uint4 v = {0u, 0u, 0u, 0u};
            if ((unsigned)dd < 8u && (unsigned)hh < 56u && (unsigned)ww < 56u) {
                size_t sp = (size_t)(b * 8 + dd) * PLANE + hh * 56 + ww;
                v = *(const uint4*)(in_cl + sp * 128 + k8);
            }
            *(uint4*)&sA[m][k8] = v;
        }
        // stage W tap slice: 128 oc x 128 ic
        const u16* wp = wt27 + (size_t)ko * 16384;
        #pragma unroll
        for (int i = 0; i < 8; i++) {
            int unit = tid + i * 256;
            int oc = unit >> 4, k8 = (unit & 15) << 3;
            *(uint4*)&sB[oc][k8] = *(const uint4*)(wp + oc * 128 + k8);
        }
        __syncthreads();
        #pragma unroll
        for (int kk = 0; kk < 4; kk++) {
            short8 afr[4], bfr[2];
            #pragma unroll
            for (int mt = 0; mt < 4; mt++)
                afr[mt] = *(const short8*)&sA[mt*16 + l15][kk*32 + quad*8];
            #pragma unroll
            for (int nt = 0; nt < 2; nt++)
                bfr[nt] = *(const short8*)&sB[n0 + nt*16 + l15][kk*32 + quad*8];
            #pragma unroll
            for (int mt = 0; mt < 4; mt++)
                #pragma unroll
                for (int nt = 0; nt < 2; nt++)
                    acc[mt][nt] = __builtin_amdgcn_mfma_f32_16x16x32_bf16(
                        afr[mt], bfr[nt], acc[mt][nt], 0, 0, 0);
        }
    }

    // bias + leaky + residual (residual into the ACC so both outputs get it)
    #pragma unroll
    for (int nt = 0; nt < 2; nt++) {
        int oc = n0 + nt*16 + l15;
        float bv = bias[oc];
        #pragma unroll
        for (int mt = 0; mt < 4; mt++) {
            int m = mt*16 + quad*4;
            #pragma unroll
            for (int r = 0; r < 4; r++) {
                float v = acc[mt][nt][r] + bv;
                if (leaky) v = (v >= 0.f) ? v : 0.01f * v;
                if (res_cl) v += b2f(res_cl[(size_t)(t0 + m + r) * 128 + oc]);
                acc[mt][nt][r] = v;
            }
        }
    }

    if (out_cl) {
        #pragma unroll
        for (int mt = 0; mt < 4; mt++) {
            int m = mt*16 + quad*4;
            #pragma unroll
            for (int nt = 0; nt < 2; nt++) {
                int oc = n0 + nt*16 + l15;
                #pragma unroll
                for (int r = 0; r < 4; r++)
                    out_cl[(size_t)(t0 + m + r) * 128 + oc] = f2b(acc[mt][nt][r]);
            }
        }
    }

    if (out_f32) {
        __syncthreads();
        float* sT = (float*)&sB[0][0];   // [128][65] f32 = 33,280 B <= 34,816
        #pragma unroll
        for (int mt = 0; mt < 4; mt++) {
            int m = mt*16 + quad*4;
            #pragma unroll
            for (int nt = 0; nt < 2; nt++) {
                int oc = n0 + nt*16 + l15;
                #pragma unroll
                for (int r = 0; r < 4; r++)
                    sT[oc * 65 + m + r] = acc[mt][nt][r];
            }
        }
        __syncthreads();
        int oc = tid >> 1, half = tid & 1;
        size_t obase = ((size_t)b * 256 + oc_base + oc) * SPAT + sp0 + half * 32;
        const float* row = &sT[oc * 65 + half * 32];
        for (int j = 0; j < 32; j++) out_f32[obase + j] = row[j];
    }
}

// ---------------- launch ----------------------------------------------------
extern "C" void kernel_launch(void* const* d_in, const int* in_sizes, int n_in,
                              void* d_out, int out_size, void* d_ws, size_t ws_size,
                              hipStream_t stream)
{
    const float* input  = (const float*)d_in[0];
    const float* n1w    = (const float*)d_in[1];
    const float* n1b    = (const float*)d_in[2];
    const float* n2w    = (const float*)d_in[3];
    const float* n2b    = (const float*)d_in[4];
    const float* wqkv   = (const float*)d_in[5];
    const float* wprojw = (const float*)d_in[6];
    const float* wprojb = (const float*)d_in[7];
    const float* wbias  = (const float*)d_in[8];
    const float* gqkv   = (const float*)d_in[9];
    const float* gprojw = (const float*)d_in[10];
    const float* gprojb = (const float*)d_in[11];
    const float* gbias  = (const float*)d_in[12];
    const float* f1c1w  = (const float*)d_in[13];
    const float* f1c1b  = (const float*)d_in[14];
    const float* f1c2w  = (const float*)d_in[15];
    const float* f1c2b  = (const float*)d_in[16];
    const float* g1c1w  = (const float*)d_in[17];
    const float* g1c1b  = (const float*)d_in[18];
    const float* g1c2w  = (const float*)d_in[19];
    const float* g1c2b  = (const float*)d_in[20];

    char* ws = (char*)d_ws;
    u16* xln   = (u16*)(ws);                    // 25,690,112 B (later: y)
    u16* qkv   = (u16*)(ws + 25690112);         // 77,070,336 B (later: conv bufs)
    u16* attnb = (u16*)(ws + 102760448);        // 25,690,112 B
    u16* xw    = (u16*)(ws + 128450560);        // 25,690,112 B -> total 154,140,672
    u16* y  = xln;                              // xln dead after grid-qkv gemm
    // conv-phase aliases inside qkv region (qkv dead after grid attention):
    u16* s1   = qkv;                            // 12,845,056 B
    u16* s2   = (u16*)(ws + 25690112 + 12845056);
    u16* tb   = (u16*)(ws + 25690112 + 25690112);
    u16* y1cl = (u16*)(ws + 25690112 + 38535168);
    u16* cw0  = (u16*)(ws + 25690112 + 51380224);   // 884,736 B each
    u16* cw1  = cw0 + 442368;
    u16* cw2  = cw1 + 442368;
    u16* cw3  = cw2 + 442368;

    float* outp = (float*)d_out;

    // 1) LN1
    ln1_kernel<<<196, 256, 0, stream>>>(input, n1w, n1b, xln);
    // 2) window qkv (M=50176, N=768)
    gemm_mfma_kernel<<<dim3(392, 6), 256, 0, stream>>>(xln, wqkv, nullptr, nullptr, qkv, 768);
    // 3) window attention
    attn_kernel<<<dim3(512, 4), 256, 0, stream>>>(qkv, wbias, attnb, 0);
    // 4) window proj -> xw
    gemm_mfma_kernel<<<dim3(392, 2), 256, 0, stream>>>(attnb, wprojw, wprojb, nullptr, xw, 256);
    // 5) LN2 -> xln
    ln2_kernel<<<12544, 256, 0, stream>>>(xw, n2w, n2b, xln);
    // 6) grid qkv
    gemm_mfma_kernel<<<dim3(392, 6), 256, 0, stream>>>(xln, gqkv, nullptr, nullptr, qkv, 768);
    // 7) grid attention
    attn_kernel<<<dim3(512, 4), 256, 0, stream>>>(qkv, gbias, attnb, 1);
    // 8) grid proj + xw residual -> y (aliases dead xln)
    gemm_mfma_kernel<<<dim3(392, 2), 256, 0, stream>>>(attnb, gprojw, gprojb, xw, y, 256);
    // 9) s = input + y -> channel-last halves
    ssplit_cl_kernel<<<784, 256, 0, stream>>>(input, y, s1, s2);
    // 10) conv weight transforms (f32 OIDHW -> bf16 [27][oc][ic])
    convw_kernel<<<1728, 256, 0, stream>>>(f1c1w, cw0);
    convw_kernel<<<1728, 256, 0, stream>>>(f1c2w, cw1);
    convw_kernel<<<1728, 256, 0, stream>>>(g1c1w, cw2);
    convw_kernel<<<1728, 256, 0, stream>>>(g1c2w, cw3);
    // 11) t = leaky(conv(s2, f1c1))
    conv_mfma_kernel<<<784, 256, 0, stream>>>(s2, cw0, f1c1b, nullptr, tb, nullptr, 0, 1);
    // 12) y1 = s1 + conv(t, f1c2) -> d_out[:,0:128] and y1cl
    conv_mfma_kernel<<<784, 256, 0, stream>>>(tb, cw1, f1c2b, s1, y1cl, outp, 0, 0);
    // 13) t = leaky(conv(y1, g1c1))
    conv_mfma_kernel<<<784, 256, 0, stream>>>(y1cl, cw2, g1c1b, nullptr, tb, nullptr, 0, 1);
    // 14) y2 = s2 + conv(t, g1c2) -> d_out[:,128:256]
    conv_mfma_kernel<<<784, 256, 0, stream>>>(tb, cw3, g1c2b, s2, nullptr, outp, 128, 0);
}

// Round 5
// 961.773 us; speedup vs baseline: 7.9187x; 1.8876x over previous
//
#include <hip/hip_runtime.h>
#include <stdint.h>

// MixBlock3D: B=2 C=256 D=8 H=56 W=56, GWS=(2,7,7). I/O f32, intermediates bf16.
// Round 5: MFMA attention (QK^T + PV on matrix cores, 98->112 padded tiles,
// separable rel-pos bias, unnormalized-exp P with epilogue row scale).

typedef unsigned short u16;
typedef __attribute__((ext_vector_type(8))) short short8;  // 8 bf16 = 4 VGPR
typedef __attribute__((ext_vector_type(4))) float f32x4;   // 4 fp32 acc

#define TOK   50176
#define CH    256
#define SPAT  25088
#define PLANE 3136

__device__ __forceinline__ float b2f(u16 u) {
    union { uint32_t i; float f; } v; v.i = ((uint32_t)u) << 16; return v.f;
}
__device__ __forceinline__ u16 f2b(float f) {
    union { float f; uint32_t i; } v; v.f = f;
    uint32_t i = v.i;
    uint32_t r = i + 0x7FFFu + ((i >> 16) & 1u);
    return (u16)(r >> 16);
}

// ---------------- LN1: NCDHW f32 -> token-major (t, c) bf16 -----------------
__global__ __launch_bounds__(256) void ln1_kernel(
    const float* __restrict__ x, const float* __restrict__ w,
    const float* __restrict__ bsh, u16* __restrict__ out)
{
    int t = blockIdx.x * 256 + threadIdx.x;
    int b = t / SPAT, sp = t % SPAT;
    const float* px = x + (size_t)b * CH * SPAT + sp;
    float s = 0.f, ss = 0.f;
    for (int c = 0; c < CH; c++) { float v = px[(size_t)c * SPAT]; s += v; ss += v * v; }
    float mean = s * (1.0f / CH);
    float var  = ss * (1.0f / CH) - mean * mean;
    float rstd = rsqrtf(var + 1e-5f);
    u16* po = out + (size_t)t * CH;
    for (int c = 0; c < CH; c++) {
        float v = (px[(size_t)c * SPAT] - mean) * rstd * w[c] + bsh[c];
        po[c] = f2b(v);
    }
}

// ---------------- LN2: token-major bf16 -> token-major bf16 -----------------
__global__ __launch_bounds__(256) void ln2_kernel(
    const u16* __restrict__ x, const float* __restrict__ w,
    const float* __restrict__ bsh, u16* __restrict__ out)
{
    int wave = threadIdx.x >> 6, lane = threadIdx.x & 63;
    int t = blockIdx.x * 4 + wave;
    const u16* px = x + (size_t)t * CH + lane * 4;
    ushort4 v4 = *(const ushort4*)px;
    float v0 = b2f(v4.x), v1 = b2f(v4.y), v2 = b2f(v4.z), v3 = b2f(v4.w);
    float s = v0 + v1 + v2 + v3;
    float ss = v0*v0 + v1*v1 + v2*v2 + v3*v3;
    for (int o = 32; o > 0; o >>= 1) {
        s  += __shfl_xor(s,  o, 64);
        ss += __shfl_xor(ss, o, 64);
    }
    float mean = s * (1.0f / CH);
    float rstd = rsqrtf(ss * (1.0f / CH) - mean * mean + 1e-5f);
    float4 w4 = *(const float4*)(w + lane * 4);
    float4 b4 = *(const float4*)(bsh + lane * 4);
    ushort4 o4;
    o4.x = f2b((v0 - mean) * rstd * w4.x + b4.x);
    o4.y = f2b((v1 - mean) * rstd * w4.y + b4.y);
    o4.z = f2b((v2 - mean) * rstd * w4.z + b4.z);
    o4.w = f2b((v3 - mean) * rstd * w4.w + b4.w);
    *(ushort4*)(out + (size_t)t * CH + lane * 4) = o4;
}

// ---- MFMA GEMM: C[M,Nout slice] = A[M,256](bf16) @ B[N,256]^T(f32 weights) ----
__global__ __launch_bounds__(256) void gemm_mfma_kernel(
    const u16* __restrict__ A, const float* __restrict__ B,
    const float* __restrict__ bias, const u16* __restrict__ res,
    u16* __restrict__ C, int Nout)
{
    __shared__ u16 sAg[128][72];
    __shared__ u16 sBg[128][72];
    int tid = threadIdx.x;
    int m0 = blockIdx.x * 128, n0g = blockIdx.y * 128;
    int lane = tid & 63, wv = tid >> 6;
    int quad = lane >> 4, l15 = lane & 15;
    int mw = (wv & 1) * 64, nw = (wv >> 1) * 64;

    f32x4 zz = {0.f, 0.f, 0.f, 0.f};
    f32x4 acc[4][4];
    #pragma unroll
    for (int i = 0; i < 4; i++)
        #pragma unroll
        for (int j = 0; j < 4; j++) acc[i][j] = zz;

    for (int kc = 0; kc < 256; kc += 64) {
        __syncthreads();
        #pragma unroll
        for (int i = 0; i < 4; i++) {
            int unit = tid + i * 256;
            int row = unit >> 3, k8 = (unit & 7) << 3;
            *(uint4*)&sAg[row][k8] = *(const uint4*)(A + (size_t)(m0 + row) * 256 + kc + k8);
        }
        #pragma unroll
        for (int i = 0; i < 8; i++) {
            int unit = tid + i * 256;
            int row = unit >> 4, k4 = (unit & 15) << 2;
            float4 v = *(const float4*)(B + (size_t)(n0g + row) * 256 + kc + k4);
            ushort4 p;
            p.x = f2b(v.x); p.y = f2b(v.y); p.z = f2b(v.z); p.w = f2b(v.w);
            *(ushort4*)&sBg[row][k4] = p;
        }
        __syncthreads();
        #pragma unroll
        for (int kk = 0; kk < 2; kk++) {
            short8 afr[4], bfr[4];
            #pragma unroll
            for (int mt = 0; mt < 4; mt++)
                afr[mt] = *(const short8*)&sAg[mw + mt*16 + l15][kk*32 + quad*8];
            #pragma unroll
            for (int nt = 0; nt < 4; nt++)
                bfr[nt] = *(const short8*)&sBg[nw + nt*16 + l15][kk*32 + quad*8];
            #pragma unroll
            for (int mt = 0; mt < 4; mt++)
                #pragma unroll
                for (int nt = 0; nt < 4; nt++)
                    acc[mt][nt] = __builtin_amdgcn_mfma_f32_16x16x32_bf16(
                        afr[mt], bfr[nt], acc[mt][nt], 0, 0, 0);
        }
    }

    #pragma unroll
    for (int nt = 0; nt < 4; nt++) {
        int n = n0g + nw + nt*16 + l15;
        float bv = bias ? bias[n] : 0.f;
        #pragma unroll
        for (int mt = 0; mt < 4; mt++) {
            int m = m0 + mw + mt*16 + quad*4;
            #pragma unroll
            for (int r = 0; r < 4; r++) {
                float v = acc[mt][nt][r] + bv;
                size_t off = (size_t)(m + r) * Nout + n;
                if (res) v += b2f(res[off]);
                C[off] = f2b(v);
            }
        }
    }
}

// ---------------- MFMA Attention: one block per (group, head) ---------------
// N=98 tokens padded to 112 (7 tiles). QK^T and PV on matrix cores.
// P stored as unnormalized exp (bf16); 1/rowsum applied in PV epilogue.
__global__ __launch_bounds__(256) void attn_mfma_kernel(
    const u16* __restrict__ qkv, const float* __restrict__ btab,
    u16* __restrict__ outp, int mode)
{
    __shared__ u16 sKV[8704];        // 17,408 B: K [112][72] then V^T [64][136]
    __shared__ u16 sS[112][136];     // 30,464 B: logits -> unnormalized exp
    __shared__ float sBias[507];
    __shared__ int sTok[112];
    __shared__ int sEnc[112];
    __shared__ float sInv[112];

    int g = blockIdx.x, head = blockIdx.y, tid = threadIdx.x;
    int b  = g >> 8;
    int gd = (g >> 6) & 3, gh = (g >> 3) & 7, gw = g & 7;

    int lane = tid & 63, wv = tid >> 6;
    int quad = lane >> 4, l15 = lane & 15;
    int mts[2] = {wv, wv + 4};       // wave-owned M tiles (wave 3: only tile 3)

    // ---- phase 0: stage tokens, enc, bias, K ----
    if (tid < 112) {
        int t = tid;
        int i = t / 49, r = t % 49, j = r / 7, k = r % 7;
        sEnc[tid] = i * 169 + j * 13 + k;
        int tokv = 0;
        if (t < 98) {
            int d, h, w;
            if (mode == 0) { d = gd*2 + i; h = gh*7 + j; w = gw*7 + k; }
            else           { d = i*4 + gd; h = j*8 + gh; w = k*8 + gw; }
            tokv = ((b*8 + d)*56 + h)*56 + w;
        }
        sTok[tid] = tokv;
    }
    for (int idx = tid; idx < 507; idx += 256) sBias[idx] = btab[idx * 4 + head];
    __syncthreads();   // sTok ready for K staging

    // K: [112 tokens][64 ch] -> sKV[row*72 + c], rows >=98 zero
    for (int idx = tid; idx < 112 * 8; idx += 256) {
        int row = idx >> 3, c8 = (idx & 7) << 3;
        uint4 v = {0u, 0u, 0u, 0u};
        if (row < 98)
            v = *(const uint4*)(qkv + (size_t)sTok[row] * 768 + 256 + head * 64 + c8);
        *(uint4*)&sKV[row * 72 + c8] = v;
    }
    __syncthreads();

    // ---- Q fragments direct from global (A-layout) ----
    short8 qf[2][2];
    #pragma unroll
    for (int mi = 0; mi < 2; mi++) {
        int mt = mts[mi];
        #pragma unroll
        for (int ks = 0; ks < 2; ks++) {
            short8 v;
            #pragma unroll
            for (int j = 0; j < 8; j++) v[j] = 0;
            int row = mt * 16 + l15;
            if (mt < 7 && row < 98)
                v = *(const short8*)(qkv + (size_t)sTok[row] * 768 + head * 64 + ks * 32 + quad * 8);
            qf[mi][ks] = v;
        }
    }

    // ---- phase 1: S = 0.125 * Q K^T + bias ----
    f32x4 zz = {0.f, 0.f, 0.f, 0.f};
    #pragma unroll
    for (int mi = 0; mi < 2; mi++) {
        int mt = mts[mi];
        if (mt >= 7) continue;
        for (int nt = 0; nt < 7; nt++) {
            f32x4 acc = zz;
            acc = __builtin_amdgcn_mfma_f32_16x16x32_bf16(
                qf[mi][0], *(const short8*)&sKV[(nt*16 + l15) * 72 + quad*8], acc, 0, 0, 0);
            acc = __builtin_amdgcn_mfma_f32_16x16x32_bf16(
                qf[mi][1], *(const short8*)&sKV[(nt*16 + l15) * 72 + 32 + quad*8], acc, 0, 0, 0);
            int n = nt * 16 + l15;
            int en = (n < 98) ? sEnc[n] : 0;
            #pragma unroll
            for (int r = 0; r < 4; r++) {
                int m = mt * 16 + quad * 4 + r;
                float v;
                if (n < 98) {
                    int em = sEnc[m < 98 ? m : 97];
                    v = acc[r] * 0.125f + sBias[em - en + 253];
                } else v = -1e30f;
                sS[m][n] = f2b(v);
            }
        }
    }
    __syncthreads();   // sS complete; sK dead

    // ---- phase 2a: stage V^T into sKV (overwrites K) ----
    // sVt[c][tok] = sKV[c*136 + tok]; zero token cols 98..127
    for (int idx = tid; idx < 64 * 30; idx += 256) {
        int c = idx / 30, t = 98 + idx % 30;
        sKV[c * 136 + t] = 0;
    }
    for (int idx = tid; idx < 98 * 8; idx += 256) {
        int tok = idx >> 3, c8 = (idx & 7) << 3;
        uint4 v = *(const uint4*)(qkv + (size_t)sTok[tok] * 768 + 512 + head * 64 + c8);
        const u16* pv = (const u16*)&v;
        #pragma unroll
        for (int j = 0; j < 8; j++) sKV[(c8 + j) * 136 + tok] = pv[j];
    }

    // ---- phase 2b: softmax (2 threads per row), store unnormalized exp ----
    {
        int row = tid >> 1, half = tid & 1;
        if (row < 112) {
            #pragma unroll
            for (int j = 0; j < 8; j++) sS[row][112 + half * 8 + j] = 0;
        }
        if (row < 98) {
            int c0 = half * 49;
            float mx = -1e30f;
            for (int j = 0; j < 49; j++) mx = fmaxf(mx, b2f(sS[row][c0 + j]));
            mx = fmaxf(mx, __shfl_xor(mx, 1, 64));
            float sum = 0.f;
            for (int j = 0; j < 49; j++) {
                float e = __expf(b2f(sS[row][c0 + j]) - mx);
                sum += e;
                sS[row][c0 + j] = f2b(e);
            }
            sum += __shfl_xor(sum, 1, 64);
            if (half == 0) sInv[row] = 1.0f / sum;
        }
    }
    __syncthreads();

    // ---- phase 3: O = P V  (K-dim = 128 padded) ----
    f32x4 po[2][4];
    #pragma unroll
    for (int mi = 0; mi < 2; mi++)
        #pragma unroll
        for (int nt = 0; nt < 4; nt++) po[mi][nt] = zz;

    #pragma unroll
    for (int mi = 0; mi < 2; mi++) {
        int mt = mts[mi];
        if (mt >= 7) continue;
        for (int ks = 0; ks < 4; ks++) {
            short8 ap = *(const short8*)&sS[mt*16 + l15][ks*32 + quad*8];
            #pragma unroll
            for (int nt = 0; nt < 4; nt++) {
                short8 bv = *(const short8*)&sKV[(nt*16 + l15) * 136 + ks*32 + quad*8];
                po[mi][nt] = __builtin_amdgcn_mfma_f32_16x16x32_bf16(ap, bv, po[mi][nt], 0, 0, 0);
            }
        }
    }

    // ---- epilogue: scale by 1/rowsum, scatter to token-major output ----
    #pragma unroll
    for (int mi = 0; mi < 2; mi++) {
        int mt = mts[mi];
        if (mt >= 7) continue;
        #pragma unroll
        for (int r = 0; r < 4; r++) {
            int m = mt * 16 + quad * 4 + r;
            if (m >= 98) continue;
            float inv = sInv[m];
            u16* dst = outp + (size_t)sTok[m] * 256 + head * 64 + l15;
            #pragma unroll
            for (int nt = 0; nt < 4; nt++)
                dst[nt * 16] = f2b(po[mi][nt][r] * inv);
        }
    }
}

// ---- s = input(f32 NCDHW) + y(bf16 token-major) -> s1/s2 channel-last bf16 --
__global__ __launch_bounds__(256) void ssplit_cl_kernel(
    const float* __restrict__ inp, const u16* __restrict__ y,
    u16* __restrict__ s1, u16* __restrict__ s2)
{
    __shared__ float sT[64][65];
    int t0 = blockIdx.x * 64;
    int b = t0 / SPAT, sp0 = t0 % SPAT;
    int tid = threadIdx.x;
    for (int cg = 0; cg < 4; cg++) {
        __syncthreads();
        #pragma unroll
        for (int i = 0; i < 16; i++) {
            int unit = tid + i * 256;
            int cl = unit >> 6, spl = unit & 63;
            sT[spl][cl] = inp[((size_t)(b * 256 + cg * 64 + cl)) * SPAT + sp0 + spl];
        }
        __syncthreads();
        int spl = tid >> 2, c16 = (tid & 3) * 16;
        int tok = t0 + spl;
        const u16* yp = y + (size_t)tok * 256 + cg * 64 + c16;
        int cbase = cg * 64 + c16;
        u16* dst = (cbase < 128) ? (s1 + (size_t)tok * 128 + cbase)
                                 : (s2 + (size_t)tok * 128 + cbase - 128);
        #pragma unroll
        for (int j = 0; j < 16; j++) {
            float v = sT[spl][c16 + j] + b2f(yp[j]);
            dst[j] = f2b(v);
        }
    }
}

// ---- conv weight transform: f32 [oc][ic][27] -> bf16 [27][oc][ic] ----------
__global__ __launch_bounds__(256) void convw_kernel(
    const float* __restrict__ w, u16* __restrict__ o)
{
    int e = blockIdx.x * 256 + threadIdx.x;
    int k = e >> 14;
    int r = e & 16383;
    o[e] = f2b(w[(size_t)r * 27 + k]);
}

// ---- MFMA conv 3x3x3 128->128, implicit GEMM, channel-last -----------------
__global__ __launch_bounds__(256) void conv_mfma_kernel(
    const u16* __restrict__ in_cl,   // [tok][128] bf16
    const u16* __restrict__ wt27,    // [27][128 oc][128 ic] bf16
    const float* __restrict__ bias,  // [128] f32
    const u16* __restrict__ res_cl,  // nullable [tok][128] bf16 (added to acc)
    u16* __restrict__ out_cl,        // nullable [tok][128] bf16
    float* __restrict__ out_f32,     // nullable NCDHW f32 (256-ch layout)
    int oc_base, int leaky)
{
    __shared__ u16 sA[64][136];
    __shared__ u16 sB[128][136];
    __shared__ int sD[64], sHH[64], sWW[64];

    int tid = threadIdx.x;
    int t0 = blockIdx.x * 64;
    int b = t0 / SPAT, sp0 = t0 % SPAT;

    if (tid < 64) {
        int sp = sp0 + tid;
        int d = sp / PLANE, r = sp % PLANE;
        sD[tid] = d; sHH[tid] = r / 56; sWW[tid] = r % 56;
    }

    int lane = tid & 63, wv = tid >> 6;
    int quad = lane >> 4, l15 = lane & 15;
    int n0 = wv * 32;

    f32x4 zz = {0.f, 0.f, 0.f, 0.f};
    f32x4 acc[4][2];
    #pragma unroll
    for (int i = 0; i < 4; i++) { acc[i][0] = zz; acc[i][1] = zz; }

    __syncthreads();

    for (int ko = 0; ko < 27; ko++) {
        int kd = ko / 9 - 1, kh = (ko / 3) % 3 - 1, kw = ko % 3 - 1;
        __syncthreads();
        #pragma unroll
        for (int i = 0; i < 4; i++) {
            int unit = tid + i * 256;
            int m = unit >> 4, k8 = (unit & 15) << 3;
            int dd = sD[m] + kd, hh = sHH[m] + kh, ww = sWW[m] + kw;
            uint4 v = {0u, 0u, 0u, 0u};
            if ((unsigned)dd < 8u && (unsigned)hh < 56u && (unsigned)ww < 56u) {
                size_t sp = (size_t)(b * 8 + dd) * PLANE + hh * 56 + ww;
                v = *(const uint4*)(in_cl + sp * 128 + k8);
            }
            *(uint4*)&sA[m][k8] = v;
        }
        const u16* wp = wt27 + (size_t)ko * 16384;
        #pragma unroll
        for (int i = 0; i < 8; i++) {
            int unit = tid + i * 256;
            int oc = unit >> 4, k8 = (unit & 15) << 3;
            *(uint4*)&sB[oc][k8] = *(const uint4*)(wp + oc * 128 + k8);
        }
        __syncthreads();
        #pragma unroll
        for (int kk = 0; kk < 4; kk++) {
            short8 afr[4], bfr[2];
            #pragma unroll
            for (int mt = 0; mt < 4; mt++)
                afr[mt] = *(const short8*)&sA[mt*16 + l15][kk*32 + quad*8];
            #pragma unroll
            for (int nt = 0; nt < 2; nt++)
                bfr[nt] = *(const short8*)&sB[n0 + nt*16 + l15][kk*32 + quad*8];
            #pragma unroll
            for (int mt = 0; mt < 4; mt++)
                #pragma unroll
                for (int nt = 0; nt < 2; nt++)
                    acc[mt][nt] = __builtin_amdgcn_mfma_f32_16x16x32_bf16(
                        afr[mt], bfr[nt], acc[mt][nt], 0, 0, 0);
        }
    }

    // bias + leaky + residual (into ACC so both outputs get it)
    #pragma unroll
    for (int nt = 0; nt < 2; nt++) {
        int oc = n0 + nt*16 + l15;
        float bv = bias[oc];
        #pragma unroll
        for (int mt = 0; mt < 4; mt++) {
            int m = mt*16 + quad*4;
            #pragma unroll
            for (int r = 0; r < 4; r++) {
                float v = acc[mt][nt][r] + bv;
                if (leaky) v = (v >= 0.f) ? v : 0.01f * v;
                if (res_cl) v += b2f(res_cl[(size_t)(t0 + m + r) * 128 + oc]);
                acc[mt][nt][r] = v;
            }
        }
    }

    if (out_cl) {
        #pragma unroll
        for (int mt = 0; mt < 4; mt++) {
            int m = mt*16 + quad*4;
            #pragma unroll
            for (int nt = 0; nt < 2; nt++) {
                int oc = n0 + nt*16 + l15;
                #pragma unroll
                for (int r = 0; r < 4; r++)
                    out_cl[(size_t)(t0 + m + r) * 128 + oc] = f2b(acc[mt][nt][r]);
            }
        }
    }

    if (out_f32) {
        __syncthreads();
        float* sT = (float*)&sB[0][0];
        #pragma unroll
        for (int mt = 0; mt < 4; mt++) {
            int m = mt*16 + quad*4;
            #pragma unroll
            for (int nt = 0; nt < 2; nt++) {
                int oc = n0 + nt*16 + l15;
                #pragma unroll
                for (int r = 0; r < 4; r++)
                    sT[oc * 65 + m + r] = acc[mt][nt][r];
            }
        }
        __syncthreads();
        int oc = tid >> 1, half = tid & 1;
        size_t obase = ((size_t)b * 256 + oc_base + oc) * SPAT + sp0 + half * 32;
        const float* row = &sT[oc * 65 + half * 32];
        for (int j = 0; j < 32; j++) out_f32[obase + j] = row[j];
    }
}

// ---------------- launch ----------------------------------------------------
extern "C" void kernel_launch(void* const* d_in, const int* in_sizes, int n_in,
                              void* d_out, int out_size, void* d_ws, size_t ws_size,
                              hipStream_t stream)
{
    const float* input  = (const float*)d_in[0];
    const float* n1w    = (const float*)d_in[1];
    const float* n1b    = (const float*)d_in[2];
    const float* n2w    = (const float*)d_in[3];
    const float* n2b    = (const float*)d_in[4];
    const float* wqkv   = (const float*)d_in[5];
    const float* wprojw = (const float*)d_in[6];
    const float* wprojb = (const float*)d_in[7];
    const float* wbias  = (const float*)d_in[8];
    const float* gqkv   = (const float*)d_in[9];
    const float* gprojw = (const float*)d_in[10];
    const float* gprojb = (const float*)d_in[11];
    const float* gbias  = (const float*)d_in[12];
    const float* f1c1w  = (const float*)d_in[13];
    const float* f1c1b  = (const float*)d_in[14];
    const float* f1c2w  = (const float*)d_in[15];
    const float* f1c2b  = (const float*)d_in[16];
    const float* g1c1w  = (const float*)d_in[17];
    const float* g1c1b  = (const float*)d_in[18];
    const float* g1c2w  = (const float*)d_in[19];
    const float* g1c2b  = (const float*)d_in[20];

    char* ws = (char*)d_ws;
    u16* xln   = (u16*)(ws);                    // 25,690,112 B (later: y)
    u16* qkv   = (u16*)(ws + 25690112);         // 77,070,336 B (later: conv bufs)
    u16* attnb = (u16*)(ws + 102760448);        // 25,690,112 B
    u16* xw    = (u16*)(ws + 128450560);        // 25,690,112 B
    u16* y  = xln;
    u16* s1   = qkv;
    u16* s2   = (u16*)(ws + 25690112 + 12845056);
    u16* tb   = (u16*)(ws + 25690112 + 25690112);
    u16* y1cl = (u16*)(ws + 25690112 + 38535168);
    u16* cw0  = (u16*)(ws + 25690112 + 51380224);
    u16* cw1  = cw0 + 442368;
    u16* cw2  = cw1 + 442368;
    u16* cw3  = cw2 + 442368;

    float* outp = (float*)d_out;

    // 1) LN1
    ln1_kernel<<<196, 256, 0, stream>>>(input, n1w, n1b, xln);
    // 2) window qkv
    gemm_mfma_kernel<<<dim3(392, 6), 256, 0, stream>>>(xln, wqkv, nullptr, nullptr, qkv, 768);
    // 3) window attention (MFMA)
    attn_mfma_kernel<<<dim3(512, 4), 256, 0, stream>>>(qkv, wbias, attnb, 0);
    // 4) window proj -> xw
    gemm_mfma_kernel<<<dim3(392, 2), 256, 0, stream>>>(attnb, wprojw, wprojb, nullptr, xw, 256);
    // 5) LN2 -> xln
    ln2_kernel<<<12544, 256, 0, stream>>>(xw, n2w, n2b, xln);
    // 6) grid qkv
    gemm_mfma_kernel<<<dim3(392, 6), 256, 0, stream>>>(xln, gqkv, nullptr, nullptr, qkv, 768);
    // 7) grid attention (MFMA)
    attn_mfma_kernel<<<dim3(512, 4), 256, 0, stream>>>(qkv, gbias, attnb, 1);
    // 8) grid proj + xw residual -> y
    gemm_mfma_kernel<<<dim3(392, 2), 256, 0, stream>>>(attnb, gprojw, gprojb, xw, y, 256);
    // 9) s = input + y -> channel-last halves
    ssplit_cl_kernel<<<784, 256, 0, stream>>>(input, y, s1, s2);
    // 10) conv weight transforms
    convw_kernel<<<1728, 256, 0, stream>>>(f1c1w, cw0);
    convw_kernel<<<1728, 256, 0, stream>>>(f1c2w, cw1);
    convw_kernel<<<1728, 256, 0, stream>>>(g1c1w, cw2);
    convw_kernel<<<1728, 256, 0, stream>>>(g1c2w, cw3);
    // 11) t = leaky(conv(s2, f1c1))
    conv_mfma_kernel<<<784, 256, 0, stream>>>(s2, cw0, f1c1b, nullptr, tb, nullptr, 0, 1);
    // 12) y1 = s1 + conv(t, f1c2) -> d_out[:,0:128] and y1cl
    conv_mfma_kernel<<<784, 256, 0, stream>>>(tb, cw1, f1c2b, s1, y1cl, outp, 0, 0);
    // 13) t = leaky(conv(y1, g1c1))
    conv_mfma_kernel<<<784, 256, 0, stream>>>(y1cl, cw2, g1c1b, nullptr, tb, nullptr, 0, 1);
    // 14) y2 = s2 + conv(t, g1c2) -> d_out[:,128:256]
    conv_mfma_kernel<<<784, 256, 0, stream>>>(tb, cw3, g1c2b, s2, nullptr, outp, 128, 0);
}